// Round 1
// baseline (232.833 us; speedup 1.0000x reference)
//
#include <hip/hip_runtime.h>
#include <math.h>

// Problem constants (from setup_inputs): x is (B=32, C=3, H=512, W=512) fp32.
constexpr int B = 32;
constexpr int C = 3;
constexpr int H = 512;
constexpr int W = 512;
constexpr int HW = H * W;

// ---------------------------------------------------------------------------
// Prologue: per-batch affine coefficients.
// overall = fw^-1 * diag(1/l1, 1/l2, 1) * fw  with fw = rot(-theta) then
// center-translation; translation column cancels exactly to 0.
// Computed in fp64 (32 threads, negligible cost) to stay at the closed-form
// ground truth; stored fp32.
// coef layout per batch (8 floats): t00, t01, t10, t11, 0, 0, 0, 0
// ---------------------------------------------------------------------------
__global__ void coef_kernel(const float* __restrict__ thetas,
                            const float* __restrict__ l1s,
                            const float* __restrict__ l2s,
                            float* __restrict__ coef) {
    int b = threadIdx.x;
    if (b >= B) return;
    double th = -(double)thetas[b];
    double c = cos(th), s = sin(th);
    double a = 1.0 / (double)l1s[b];
    double d = 1.0 / (double)l2s[b];
    double t00 = a * c * c + d * s * s;
    double t01 = c * s * (d - a);
    double t11 = a * s * s + d * c * c;
    float* cf = coef + b * 8;
    cf[0] = (float)t00;
    cf[1] = (float)t01;
    cf[2] = (float)t01;  // t10 == t01 (symmetric)
    cf[3] = (float)t11;
    cf[4] = 0.0f; cf[5] = 0.0f; cf[6] = 0.0f; cf[7] = 0.0f;
}

// ---------------------------------------------------------------------------
// Main warp kernel: 4 consecutive w-pixels per thread (float4 stores per
// channel). 256 threads = 2 rows of 512 per block. Grid (H/2, B).
// Loads are exec-mask predicated: fully-OOB lanes issue no memory traffic
// (big win here since lambda<1 => zoom-out => large zero border).
// Indices are clamped before use so no OOB address is ever formed.
// ---------------------------------------------------------------------------
__global__ __launch_bounds__(256)
void warp_kernel(const float* __restrict__ x,
                 const float* __restrict__ coef,
                 float* __restrict__ out) {
    const int tid = threadIdx.x;
    const int b  = blockIdx.y;
    const int h  = (blockIdx.x << 1) | (tid >> 7);
    const int w0 = (tid & 127) << 2;

    const float* cf = coef + b * 8;
    const float t00 = cf[0], t01 = cf[1], t10 = cf[2], t11 = cf[3];

    // Reference arithmetic order:
    //   X = (w+0.5)*(2/W)-1 ; Y = (h+0.5)*(2/H)-1
    //   gridx = t00*X + t01*Y ; gx = (gridx+1)*(W/2) - 0.5   (same for y)
    const float Y = ((float)h + 0.5f) * (2.0f / (float)H) - 1.0f;

    float r[C][4];

    const float* __restrict__ base = x + (size_t)b * C * HW;

    #pragma unroll
    for (int j = 0; j < 4; ++j) {
        const float X = ((float)(w0 + j) + 0.5f) * (2.0f / (float)W) - 1.0f;
        const float gridx = t00 * X + t01 * Y;
        const float gridy = t10 * X + t11 * Y;
        const float gx = (gridx + 1.0f) * ((float)W * 0.5f) - 0.5f;
        const float gy = (gridy + 1.0f) * ((float)H * 0.5f) - 0.5f;

        const float x0f = floorf(gx), y0f = floorf(gy);
        const float wx1 = gx - x0f, wx0 = 1.0f - wx1;
        const float wy1 = gy - y0f, wy0 = 1.0f - wy1;

        const int x0 = (int)x0f, y0 = (int)y0f;
        const int x1 = x0 + 1,  y1 = y0 + 1;

        const bool vx0 = ((unsigned)x0 < (unsigned)W);
        const bool vx1 = ((unsigned)x1 < (unsigned)W);
        const bool vy0 = ((unsigned)y0 < (unsigned)H);
        const bool vy1 = ((unsigned)y1 < (unsigned)H);

        // Clamped, always-in-range flat indices.
        const int xc0 = min(max(x0, 0), W - 1);
        const int xc1 = min(max(x1, 0), W - 1);
        const int yc0 = min(max(y0, 0), H - 1);
        const int yc1 = min(max(y1, 0), H - 1);
        const int i00 = yc0 * W + xc0;
        const int i01 = yc0 * W + xc1;
        const int i10 = yc1 * W + xc0;
        const int i11 = yc1 * W + xc1;

        const float w00 = wy0 * wx0, w01 = wy0 * wx1;
        const float w10 = wy1 * wx0, w11 = wy1 * wx1;

        #pragma unroll
        for (int ch = 0; ch < C; ++ch) {
            const float* __restrict__ p = base + ch * HW;
            float v00 = 0.0f, v01 = 0.0f, v10 = 0.0f, v11 = 0.0f;
            if (vy0 && vx0) v00 = p[i00];
            if (vy0 && vx1) v01 = p[i01];
            if (vy1 && vx0) v10 = p[i10];
            if (vy1 && vx1) v11 = p[i11];
            // Same accumulation order as the reference.
            r[ch][j] = v00 * w00 + v01 * w01 + v10 * w10 + v11 * w11;
        }
    }

    const size_t obase = (size_t)b * C * HW + (size_t)h * W + (size_t)w0;
    #pragma unroll
    for (int ch = 0; ch < C; ++ch) {
        float4 v = make_float4(r[ch][0], r[ch][1], r[ch][2], r[ch][3]);
        *reinterpret_cast<float4*>(out + obase + (size_t)ch * HW) = v;
    }
}

extern "C" void kernel_launch(void* const* d_in, const int* in_sizes, int n_in,
                              void* d_out, int out_size, void* d_ws, size_t ws_size,
                              hipStream_t stream) {
    const float* x       = (const float*)d_in[0];
    const float* thetas  = (const float*)d_in[1];
    const float* l1s     = (const float*)d_in[2];
    const float* l2s     = (const float*)d_in[3];
    float* out           = (float*)d_out;
    float* coef          = (float*)d_ws;  // 32*8 floats = 1 KB

    coef_kernel<<<1, 64, 0, stream>>>(thetas, l1s, l2s, coef);
    warp_kernel<<<dim3(H / 2, B), 256, 0, stream>>>(x, coef, out);
}

// Round 2
// 188.199 us; speedup vs baseline: 1.2372x; 1.2372x over previous
//
#include <hip/hip_runtime.h>
#include <math.h>

// Problem constants (from setup_inputs): x is (B=32, C=3, H=512, W=512) fp32.
constexpr int B = 32;
constexpr int C = 3;
constexpr int H = 512;
constexpr int W = 512;
constexpr int HW = H * W;

// ---------------------------------------------------------------------------
// Single-kernel affine warp, bilinear, zero padding.
//
// Affine reduction: overall = fw^-1 * diag(1/l1,1/l2,1) * fw with
// fw = rot(-theta)·trans; the translation cancels exactly, leaving a pure
// 2x2 linear map: t00 = a c^2 + d s^2, t01 = t10 = c s (d-a),
// t11 = a s^2 + d c^2 with a=1/l1, d=1/l2, c=cos(-th), s=sin(-th).
// Computed per-block in fp64 by thread 0 (deterministic, identical across
// blocks of the same batch), broadcast via LDS.
//
// Mapping: block = 256 threads = 4 waves; each wave owns 256 consecutive
// output pixels of one row (lane-consecutive => adjacent lanes sample
// source points only t00 px apart => within-instruction line coalescing).
// Each thread handles 4 pixels strided by 64 lanes.
//
// Gathers: the two bilinear x-neighbors are loaded with ONE float2 load
// (clamp base to [0,W-2], select/mask for edges) => 6 loads/pixel instead
// of 12. Rows predicated; fully-OOB threads skip all loads/math.
// ---------------------------------------------------------------------------
__global__ __launch_bounds__(256)
void warp_kernel(const float* __restrict__ x,
                 const float* __restrict__ thetas,
                 const float* __restrict__ l1s,
                 const float* __restrict__ l2s,
                 float* __restrict__ out) {
    const int b = blockIdx.y;

    __shared__ float sc[4];
    if (threadIdx.x == 0) {
        double th = -(double)thetas[b];
        double c = cos(th), s = sin(th);
        double a = 1.0 / (double)l1s[b];
        double d = 1.0 / (double)l2s[b];
        sc[0] = (float)(a * c * c + d * s * s);
        sc[1] = (float)(c * s * (d - a));
        sc[2] = sc[1];
        sc[3] = (float)(a * s * s + d * c * c);
    }
    __syncthreads();
    const float t00 = sc[0], t01 = sc[1], t10 = sc[2], t11 = sc[3];

    const int tid   = threadIdx.x;
    const int lane  = tid & 63;
    const int wv    = tid >> 6;                 // wave id 0..3
    const int h     = (blockIdx.x << 1) | (wv >> 1);
    const int wbase = (wv & 1) << 8;            // 0 or 256

    // Reference arithmetic: X=(w+0.5)*(2/W)-1, gx=(gridx+1)*(W/2)-0.5
    const float Y = ((float)h + 0.5f) * (2.0f / (float)H) - 1.0f;

    // ---- geometry for the 4 pixels ----
    int   xb[4], row0[4], row1[4];
    bool  xeq[4], vx0[4], vx1[4], pr0[4], pr1[4];
    float w00[4], w01[4], w10[4], w11[4];
    bool any_valid = false;

    #pragma unroll
    for (int j = 0; j < 4; ++j) {
        const int w = wbase + (j << 6) + lane;
        const float X = ((float)w + 0.5f) * (2.0f / (float)W) - 1.0f;
        const float gx = (t00 * X + t01 * Y + 1.0f) * ((float)W * 0.5f) - 0.5f;
        const float gy = (t10 * X + t11 * Y + 1.0f) * ((float)H * 0.5f) - 0.5f;

        const float x0f = floorf(gx), y0f = floorf(gy);
        const float wx1 = gx - x0f, wx0 = 1.0f - wx1;
        const float wy1 = gy - y0f, wy0 = 1.0f - wy1;

        const int x0 = (int)x0f, y0 = (int)y0f;
        const int x1 = x0 + 1,  y1 = y0 + 1;

        vx0[j] = ((unsigned)x0 < (unsigned)W);
        vx1[j] = ((unsigned)x1 < (unsigned)W);
        const bool vy0 = ((unsigned)y0 < (unsigned)H);
        const bool vy1 = ((unsigned)y1 < (unsigned)H);

        const int xbj = min(max(x0, 0), W - 2);
        xb[j]  = xbj;
        xeq[j] = (x0 == xbj);
        const bool anyx = vx0[j] || vx1[j];
        pr0[j] = vy0 && anyx;
        pr1[j] = vy1 && anyx;
        any_valid = any_valid || pr0[j] || pr1[j];

        row0[j] = min(max(y0, 0), H - 1) * W + xbj;
        row1[j] = min(max(y1, 0), H - 1) * W + xbj;

        w00[j] = wy0 * wx0; w01[j] = wy0 * wx1;
        w10[j] = wy1 * wx0; w11[j] = wy1 * wx1;
    }

    float r[C][4];
    #pragma unroll
    for (int ch = 0; ch < C; ++ch)
        #pragma unroll
        for (int j = 0; j < 4; ++j) r[ch][j] = 0.0f;

    if (any_valid) {
        const float* __restrict__ base = x + (size_t)b * C * HW;
        #pragma unroll
        for (int j = 0; j < 4; ++j) {
            #pragma unroll
            for (int ch = 0; ch < C; ++ch) {
                const float* __restrict__ p = base + ch * HW;
                float2 a0 = make_float2(0.0f, 0.0f);
                float2 a1 = make_float2(0.0f, 0.0f);
                if (pr0[j]) a0 = *reinterpret_cast<const float2*>(p + row0[j]);
                if (pr1[j]) a1 = *reinterpret_cast<const float2*>(p + row1[j]);
                const float v00 = vx0[j] ? (xeq[j] ? a0.x : a0.y) : 0.0f;
                const float v01 = vx1[j] ? (xeq[j] ? a0.y : a0.x) : 0.0f;
                const float v10 = vx0[j] ? (xeq[j] ? a1.x : a1.y) : 0.0f;
                const float v11 = vx1[j] ? (xeq[j] ? a1.y : a1.x) : 0.0f;
                r[ch][j] = v00 * w00[j] + v01 * w01[j] + v10 * w10[j] + v11 * w11[j];
            }
        }
    }

    const size_t obase = (size_t)b * C * HW + (size_t)h * W + (size_t)wbase + lane;
    #pragma unroll
    for (int ch = 0; ch < C; ++ch) {
        #pragma unroll
        for (int j = 0; j < 4; ++j) {
            out[obase + (size_t)ch * HW + (j << 6)] = r[ch][j];
        }
    }
}

extern "C" void kernel_launch(void* const* d_in, const int* in_sizes, int n_in,
                              void* d_out, int out_size, void* d_ws, size_t ws_size,
                              hipStream_t stream) {
    const float* x      = (const float*)d_in[0];
    const float* thetas = (const float*)d_in[1];
    const float* l1s    = (const float*)d_in[2];
    const float* l2s    = (const float*)d_in[3];
    float* out          = (float*)d_out;

    warp_kernel<<<dim3(H / 2, B), 256, 0, stream>>>(x, thetas, l1s, l2s, out);
}